// Round 9
// baseline (224.014 us; speedup 1.0000x reference)
//
#include <hip/hip_runtime.h>

typedef unsigned short ushort_t;
typedef short bf16x8 __attribute__((ext_vector_type(8)));
typedef float f32x4 __attribute__((ext_vector_type(4)));

#define B_ 128
#define L_ 200
#define D_ 128
#define M_ 64

// ---------- helpers ----------
__device__ __forceinline__ float fast_sigmoid(float x) {
    return 1.f / (1.f + __expf(-x));
}

__device__ __forceinline__ float fast_tanh(float x) {
    float xc = fminf(fmaxf(x, -15.f), 15.f);
    float e = __expf(2.f * xc);
    return (e - 1.f) / (e + 1.f);
}

__device__ __forceinline__ float bf2f(ushort_t h) {
    union { unsigned int u; float f; } x;
    x.u = ((unsigned int)h) << 16;
    return x.f;
}

__device__ __forceinline__ ushort_t f2bf(float f) {
    union { float f; unsigned int u; } x;
    x.f = f;
    unsigned int u = x.u;
    unsigned int r = (u + 0x7FFFu + ((u >> 16) & 1u)) >> 16;  // RNE
    return (ushort_t)r;
}

__device__ __forceinline__ uint4 pack8(float4 a, float4 b) {
    uint4 u;
    u.x = (unsigned)f2bf(a.x) | ((unsigned)f2bf(a.y) << 16);
    u.y = (unsigned)f2bf(a.z) | ((unsigned)f2bf(a.w) << 16);
    u.z = (unsigned)f2bf(b.x) | ((unsigned)f2bf(b.y) << 16);
    u.w = (unsigned)f2bf(b.z) | ((unsigned)f2bf(b.w) << 16);
    return u;
}

// ---------- workspace layout (float offsets) ----------
#define F_WQ   0u          // 1638400  w       (B*L, 64)
#define F_EAQ  1638400u    // 6553600  e,a interleaved (B*L, 128, 2)
#define F_FKQ  8192000u    // 3276800  fk      (B*L, 128)
#define F_RD   11468800u   // rd as bf16 A-frag pack: 3276800 ushorts (uses half)
#define F_DIFF 14745600u   //   25600  que_diff (B*L)
#define F_PACK 14771200u   // weight bf16 pack region
#define WPACK_N 57344
#define FPACK_N 16384

// ---------- K0: pack weights into bf16 MFMA-B fragment order ----------
__global__ __launch_bounds__(256) void k_pack(
    const float* __restrict__ Mk, const float* __restrict__ eW,
    const float* __restrict__ aW, const float* __restrict__ fW,
    ushort_t* __restrict__ Wpack, ushort_t* __restrict__ Fpack)
{
    int i = blockIdx.x * 256 + threadIdx.x;
    if (i < WPACK_N) {
        int g = i >> 9, lane = (i >> 3) & 63, j = i & 7;
        int nt = g >> 2, ks = g & 3;
        int col = nt * 16 + (lane & 15);
        int d = ks * 32 + ((lane >> 4) << 3) + j;
        float v;
        if (col < 64)       v = Mk[col * 128 + d];
        else if (col < 192) v = eW[(col - 64) * 128 + d];
        else if (col < 320) v = aW[(col - 192) * 128 + d];
        else                v = fW[(col - 320) * 256 + 128 + d];  // right half: k
        Wpack[i] = f2bf(v);
    } else if (i < WPACK_N + FPACK_N) {
        int e = i - WPACK_N;
        int g = e >> 9, lane = (e >> 3) & 63, j = e & 7;
        int nt = g >> 2, ks = g & 3;
        int col = nt * 16 + (lane & 15);
        int d = ks * 32 + ((lane >> 4) << 3) + j;
        Fpack[e] = f2bf(fW[col * 256 + d]);  // left half: reads
    }
}

__device__ __forceinline__ void loadB4(const ushort_t* __restrict__ base,
                                       int nt, int lane, bf16x8* b) {
    const ushort_t* p = base + (nt * 256 + lane) * 8;
    b[0] = *(const bf16x8*)(p);
    b[1] = *(const bf16x8*)(p + 512);
    b[2] = *(const bf16x8*)(p + 1024);
    b[3] = *(const bf16x8*)(p + 1536);
}

// ---------- K1: unified MFMA gather+projections+softmax+diff ----------
// 400 blocks x 512 thr. One gather per 64-pos group (k and v both staged).
// waves 0-3 (nh=0): logits nt0-3 + fk nt20-27 (A=k), then softmax
// waves 4-7 (nh=1): e nt4-11 paired with a nt12-19 (A=v), then diff (from LDS k)
__global__ __launch_bounds__(512) void k_pre_mfma(
    const int* __restrict__ q, const int* __restrict__ r,
    const float* __restrict__ k_emb, const float* __restrict__ v_emb,
    const ushort_t* __restrict__ Wpack,
    const float* __restrict__ e_b, const float* __restrict__ a_b,
    const float* __restrict__ df_W, const float* __restrict__ df_b,
    float* __restrict__ wq, float* __restrict__ eaq,
    float* __restrict__ fkq, float* __restrict__ diffq)
{
    __shared__ ushort_t skA[8192];
    __shared__ ushort_t svA[8192];
    __shared__ float slog[64 * 68];

    const int tid = threadIdx.x;
    const int pos0 = blockIdx.x * 64;
    const int wave = tid >> 6;
    const int lane = tid & 63;
    const int mt = wave & 3;
    const int nh = wave >> 2;

    // --- single gather: stage k and v A-frags (bf16) ---
    #pragma unroll
    for (int i = 0; i < 2; i++) {
        int E = tid + 512 * i;              // 1024 entries, 8 elems each
        int mtile = E >> 8, ks = (E >> 6) & 3, le = E & 63;
        int prow = pos0 + mtile * 16 + (le & 15);
        int dof = ks * 32 + ((le >> 4) << 3);
        int qv = q[prow], rv = r[prow];
        const float4* kp = (const float4*)(k_emb + qv * 128 + dof);
        float4 ka = kp[0], kb = kp[1];
        const float4* vp = (const float4*)(v_emb + rv * 128 + dof);
        float4 va = vp[0], vb = vp[1];
        *(uint4*)&skA[E * 8] = pack8(ka, kb);
        float4 s0, s1;
        s0.x = ka.x + va.x; s0.y = ka.y + va.y; s0.z = ka.z + va.z; s0.w = ka.w + va.w;
        s1.x = kb.x + vb.x; s1.y = kb.y + vb.y; s1.z = kb.z + vb.z; s1.w = kb.w + vb.w;
        *(uint4*)&svA[E * 8] = pack8(s0, s1);
    }
    __syncthreads();

    bf16x8 A[4];
    {
        const ushort_t* src = nh ? svA : skA;
        #pragma unroll
        for (int ks = 0; ks < 4; ks++)
            A[ks] = *(const bf16x8*)&src[((mt * 4 + ks) * 64 + lane) * 8];
    }

    const int col = lane & 15;
    const int quad = lane >> 4;
    const int rbase = mt * 16 + quad * 4;

    if (nh == 0) {
        // 12 nts: j 0-3 -> nt j (logits->slog), j 4-11 -> nt j+16 (fk)
        bf16x8 Bb[2][4];
        loadB4(Wpack, 0, lane, Bb[0]);
        #pragma unroll
        for (int j = 0; j < 12; j++) {
            if (j < 11) {
                int jn = j + 1;
                loadB4(Wpack, (jn < 4) ? jn : jn + 16, lane, Bb[jn & 1]);
            }
            f32x4 acc = {0.f, 0.f, 0.f, 0.f};
            #pragma unroll
            for (int ks = 0; ks < 4; ks++)
                acc = __builtin_amdgcn_mfma_f32_16x16x32_bf16(A[ks], Bb[j & 1][ks], acc, 0, 0, 0);
            if (j < 4) {
                #pragma unroll
                for (int reg = 0; reg < 4; reg++)
                    slog[(rbase + reg) * 68 + j * 16 + col] = acc[reg];
            } else {
                int c = (j - 4) * 16 + col;
                #pragma unroll
                for (int reg = 0; reg < 4; reg++)
                    fkq[(pos0 + rbase + reg) * 128 + c] = acc[reg];
            }
        }
        // softmax over own wave's slog rows (wave-local)
        {
            int row = tid >> 2, ln = tid & 3;
            const float* lr = slog + row * 68 + ln * 16;
            float v[16];
            #pragma unroll
            for (int j = 0; j < 16; j++) v[j] = lr[j];
            float mx = v[0];
            #pragma unroll
            for (int j = 1; j < 16; j++) mx = fmaxf(mx, v[j]);
            mx = fmaxf(mx, __shfl_xor(mx, 1));
            mx = fmaxf(mx, __shfl_xor(mx, 2));
            float s = 0.f;
            #pragma unroll
            for (int j = 0; j < 16; j++) { v[j] = __expf(v[j] - mx); s += v[j]; }
            s += __shfl_xor(s, 1); s += __shfl_xor(s, 2);
            float inv = 1.f / s;
            float* wout = wq + (pos0 + row) * 64 + ln * 16;
            #pragma unroll
            for (int j = 0; j < 16; j++) wout[j] = v[j] * inv;
        }
    } else {
        // 8 paired nts: e = nt 4+i, a = nt 12+i; fused float2 store
        bf16x8 Be[2][4], Ba[2][4];
        loadB4(Wpack, 4, lane, Be[0]);
        loadB4(Wpack, 12, lane, Ba[0]);
        #pragma unroll
        for (int i = 0; i < 8; i++) {
            if (i < 7) {
                loadB4(Wpack, 5 + i, lane, Be[(i + 1) & 1]);
                loadB4(Wpack, 13 + i, lane, Ba[(i + 1) & 1]);
            }
            f32x4 ae = {0.f, 0.f, 0.f, 0.f};
            f32x4 aa = {0.f, 0.f, 0.f, 0.f};
            #pragma unroll
            for (int ks = 0; ks < 4; ks++) {
                ae = __builtin_amdgcn_mfma_f32_16x16x32_bf16(A[ks], Be[i & 1][ks], ae, 0, 0, 0);
                aa = __builtin_amdgcn_mfma_f32_16x16x32_bf16(A[ks], Ba[i & 1][ks], aa, 0, 0, 0);
            }
            int c = i * 16 + col;
            float ebv = e_b[c], abv = a_b[c];
            #pragma unroll
            for (int reg = 0; reg < 4; reg++) {
                float2 o;
                o.x = fast_sigmoid(ae[reg] + ebv);
                o.y = fast_tanh(aa[reg] + abv);
                *(float2*)(eaq + ((pos0 + rbase + reg) * 128 + c) * 2) = o;
            }
        }
        // que_diff from LDS bf16 k: 4 threads/row (one per ks)
        {
            int t2 = tid - 256;
            int row = t2 >> 2, ks = t2 & 3;
            int mtile = row >> 4, rowin = row & 15;
            float s = 0.f;
            #pragma unroll
            for (int q8 = 0; q8 < 4; q8++) {
                bf16x8 kv = *(const bf16x8*)&skA[((mtile * 4 + ks) * 64 + (q8 * 16 + rowin)) * 8];
                const float* dfp = df_W + ks * 32 + q8 * 8;
                #pragma unroll
                for (int j = 0; j < 8; j++)
                    s = fmaf(bf2f((ushort_t)kv[j]), dfp[j], s);
            }
            s += __shfl_xor(s, 1); s += __shfl_xor(s, 2);
            if (ks == 0) diffq[pos0 + row] = fast_tanh(s + df_b[0]);
        }
    }
}

// ---------- K2: scan — barrier-free, LDS-free, intra-wave m-reduce ----------
// grid 256: b = blk>>1, dh = blk&1. Block 256 thr = 4 waves.
// Wave = 4 m-quarters (lane>>4) x 16 d (lane&15); wave wv covers d chunk wv*16.
// Thread owns Mv[16] (m = s*16..s*16+16). Read-reduce = 2 intra-wave shfl_xor.
// s==0 lanes store reads as bf16 in MFMA A-frag order for k_final.
__global__ __launch_bounds__(256) void k_scan(
    const float* __restrict__ wq, const float* __restrict__ eaq,
    const float* __restrict__ Mv0, ushort_t* __restrict__ rdpack)
{
    const int tid = threadIdx.x;
    const int b = blockIdx.x >> 1;
    const int dh = blockIdx.x & 1;
    const int wv = tid >> 6;      // 0..3 -> d chunk
    const int lane = tid & 63;
    const int s = lane >> 4;      // m-quarter
    const int dl = lane & 15;
    const int d = dh * 64 + wv * 16 + dl;

    float Mv[16];
    #pragma unroll
    for (int j = 0; j < 16; j++) Mv[j] = Mv0[(s * 16 + j) * D_ + d];

    const float4* wb4 = (const float4*)(wq + b * (L_ * M_)) + s * 4;
    const float2* eab = (const float2*)eaq + b * (L_ * 128) + d;

    // store address pieces (constant per thread)
    const int pos_base = b * L_;
    const int ksd = d >> 5;
    const int q8d = (d >> 3) & 3;
    const int jd = d & 7;

    #pragma unroll 2
    for (int t = 0; t < L_; t++) {
        const float4* wp = wb4 + t * 16;
        float4 w0 = wp[0], w1 = wp[1], w2 = wp[2], w3 = wp[3];
        float2 ea = eab[t * 128];
        float ev = ea.x, av = ea.y, ne = -ev;
        float r0, r1, r2, r3;
        r0 = w0.x * Mv[0];
        r1 = w0.y * Mv[1];
        r2 = w0.z * Mv[2];
        r3 = w0.w * Mv[3];
        r0 = fmaf(w1.x, Mv[4], r0);  r1 = fmaf(w1.y, Mv[5], r1);
        r2 = fmaf(w1.z, Mv[6], r2);  r3 = fmaf(w1.w, Mv[7], r3);
        r0 = fmaf(w2.x, Mv[8], r0);  r1 = fmaf(w2.y, Mv[9], r1);
        r2 = fmaf(w2.z, Mv[10], r2); r3 = fmaf(w2.w, Mv[11], r3);
        r0 = fmaf(w3.x, Mv[12], r0); r1 = fmaf(w3.y, Mv[13], r1);
        r2 = fmaf(w3.z, Mv[14], r2); r3 = fmaf(w3.w, Mv[15], r3);
        Mv[0]  = fmaf(w0.x, fmaf(ne, Mv[0],  av), Mv[0]);
        Mv[1]  = fmaf(w0.y, fmaf(ne, Mv[1],  av), Mv[1]);
        Mv[2]  = fmaf(w0.z, fmaf(ne, Mv[2],  av), Mv[2]);
        Mv[3]  = fmaf(w0.w, fmaf(ne, Mv[3],  av), Mv[3]);
        Mv[4]  = fmaf(w1.x, fmaf(ne, Mv[4],  av), Mv[4]);
        Mv[5]  = fmaf(w1.y, fmaf(ne, Mv[5],  av), Mv[5]);
        Mv[6]  = fmaf(w1.z, fmaf(ne, Mv[6],  av), Mv[6]);
        Mv[7]  = fmaf(w1.w, fmaf(ne, Mv[7],  av), Mv[7]);
        Mv[8]  = fmaf(w2.x, fmaf(ne, Mv[8],  av), Mv[8]);
        Mv[9]  = fmaf(w2.y, fmaf(ne, Mv[9],  av), Mv[9]);
        Mv[10] = fmaf(w2.z, fmaf(ne, Mv[10], av), Mv[10]);
        Mv[11] = fmaf(w2.w, fmaf(ne, Mv[11], av), Mv[11]);
        Mv[12] = fmaf(w3.x, fmaf(ne, Mv[12], av), Mv[12]);
        Mv[13] = fmaf(w3.y, fmaf(ne, Mv[13], av), Mv[13]);
        Mv[14] = fmaf(w3.z, fmaf(ne, Mv[14], av), Mv[14]);
        Mv[15] = fmaf(w3.w, fmaf(ne, Mv[15], av), Mv[15]);
        float rd = (r0 + r1) + (r2 + r3);
        rd += __shfl_xor(rd, 16);
        rd += __shfl_xor(rd, 32);
        if (s == 0) {
            int pos = pos_base + t;
            int idx = (((pos >> 4) * 4 + ksd) * 64 + (q8d * 16 + (pos & 15))) * 8 + jd;
            rdpack[idx] = f2bf(rd);
        }
    }
}

// ---------- K3: MFMA f-GEMM, A-frags direct from rdpack; fused ab/out ----------
__global__ __launch_bounds__(512) void k_final_mfma(
    const ushort_t* __restrict__ rdpack, const float* __restrict__ fkq,
    const float* __restrict__ diffq, const ushort_t* __restrict__ Fpack,
    const float* __restrict__ f_b, const float* __restrict__ ab_W,
    const float* __restrict__ ab_b, float* __restrict__ out)
{
    __shared__ float sab[64 * 2];

    const int tid = threadIdx.x;
    const int pos0 = blockIdx.x * 64;
    const int wave = tid >> 6;
    const int lane = tid & 63;
    const int mt = wave & 3;        // m-tile
    const int half = wave >> 2;     // nt half

    const int col = lane & 15;
    const int quad = lane >> 4;
    const int rbase = mt * 16 + quad * 4;

    // A-fragments straight from the scan's bf16 A-pack (no LDS, no barrier)
    bf16x8 A[4];
    {
        const ushort_t* rp = rdpack + (blockIdx.x * 4 + mt) * 2048 + lane * 8;
        #pragma unroll
        for (int ks = 0; ks < 4; ks++)
            A[ks] = *(const bf16x8*)(rp + ks * 512);
    }

    // independent fkq loads in flight alongside A loads
    float fkv[16];
    #pragma unroll
    for (int i = 0; i < 4; i++)
        #pragma unroll
        for (int reg = 0; reg < 4; reg++)
            fkv[i * 4 + reg] = fkq[(pos0 + rbase + reg) * 128 + (half * 4 + i) * 16 + col];

    float abacc[4] = {0.f, 0.f, 0.f, 0.f};

    bf16x8 Bb[2][4];
    loadB4(Fpack, half * 4, lane, Bb[0]);
    #pragma unroll
    for (int i = 0; i < 4; i++) {
        if (i < 3) loadB4(Fpack, half * 4 + i + 1, lane, Bb[(i + 1) & 1]);
        f32x4 acc = {0.f, 0.f, 0.f, 0.f};
        #pragma unroll
        for (int ks = 0; ks < 4; ks++)
            acc = __builtin_amdgcn_mfma_f32_16x16x32_bf16(A[ks], Bb[i & 1][ks], acc, 0, 0, 0);
        int c = (half * 4 + i) * 16 + col;
        float fb = f_b[c];
        float abw = ab_W[c];
        #pragma unroll
        for (int reg = 0; reg < 4; reg++) {
            float fv = fast_tanh(acc[reg] + fkv[i * 4 + reg] + fb);
            abacc[reg] = fmaf(abw, fv, abacc[reg]);
        }
    }

    #pragma unroll
    for (int reg = 0; reg < 4; reg++) {
        float v = abacc[reg];
        v += __shfl_xor(v, 1); v += __shfl_xor(v, 2);
        v += __shfl_xor(v, 4); v += __shfl_xor(v, 8);
        abacc[reg] = v;
    }
    if (col == 0) {
        #pragma unroll
        for (int reg = 0; reg < 4; reg++)
            sab[(rbase + reg) * 2 + half] = abacc[reg];
    }
    __syncthreads();
    if (tid < 64) {
        float ab = fast_tanh(sab[tid * 2] + sab[tid * 2 + 1] + ab_b[0]);
        int pos = pos0 + tid;
        out[pos] = fast_sigmoid(3.f * ab - diffq[pos]);
    }
}

// ---------- launch ----------
extern "C" void kernel_launch(void* const* d_in, const int* in_sizes, int n_in,
                              void* d_out, int out_size, void* d_ws, size_t ws_size,
                              hipStream_t stream)
{
    const int*   q     = (const int*)d_in[0];
    const int*   r     = (const int*)d_in[1];
    const float* k_emb = (const float*)d_in[2];
    const float* v_emb = (const float*)d_in[3];
    const float* Mk    = (const float*)d_in[4];
    const float* Mv0   = (const float*)d_in[5];
    const float* f_W   = (const float*)d_in[6];
    const float* f_b   = (const float*)d_in[7];
    const float* e_W   = (const float*)d_in[8];
    const float* e_b   = (const float*)d_in[9];
    const float* a_W   = (const float*)d_in[10];
    const float* a_b   = (const float*)d_in[11];
    const float* ab_W  = (const float*)d_in[12];
    const float* ab_b  = (const float*)d_in[13];
    const float* df_W  = (const float*)d_in[14];
    const float* df_b  = (const float*)d_in[15];

    float* ws = (float*)d_ws;
    float* out = (float*)d_out;
    ushort_t* Wpack = (ushort_t*)(ws + F_PACK);
    ushort_t* Fpack = Wpack + WPACK_N;
    ushort_t* rdpack = (ushort_t*)(ws + F_RD);

    // K0: pack weights to bf16 fragment layout
    k_pack<<<288, 256, 0, stream>>>(Mk, e_W, a_W, f_W, Wpack, Fpack);

    // K1: unified MFMA projections + softmax + diff (400 blocks x 8 waves)
    k_pre_mfma<<<400, 512, 0, stream>>>(
        q, r, k_emb, v_emb, Wpack, e_b, a_b, df_W, df_b,
        ws + F_WQ, ws + F_EAQ, ws + F_FKQ, ws + F_DIFF);

    // K2: scan (128 b x 2 d-halves, 4 waves, barrier-free)
    k_scan<<<256, 256, 0, stream>>>(
        ws + F_WQ, ws + F_EAQ, Mv0, rdpack);

    // K3: final MFMA + epilogue (400 blocks x 8 waves)
    k_final_mfma<<<400, 512, 0, stream>>>(
        rdpack, ws + F_FKQ, ws + F_DIFF, Fpack,
        f_b, ab_W, ab_b, out);
}

// Round 10
// 164.134 us; speedup vs baseline: 1.3648x; 1.3648x over previous
//
#include <hip/hip_runtime.h>

typedef unsigned short ushort_t;
typedef short bf16x8 __attribute__((ext_vector_type(8)));
typedef float f32x4 __attribute__((ext_vector_type(4)));

#define B_ 128
#define L_ 200
#define D_ 128
#define M_ 64

// ---------- helpers ----------
__device__ __forceinline__ float fast_sigmoid(float x) {
    return 1.f / (1.f + __expf(-x));
}

__device__ __forceinline__ float fast_tanh(float x) {
    float xc = fminf(fmaxf(x, -15.f), 15.f);
    float e = __expf(2.f * xc);
    return (e - 1.f) / (e + 1.f);
}

__device__ __forceinline__ float bf2f(ushort_t h) {
    union { unsigned int u; float f; } x;
    x.u = ((unsigned int)h) << 16;
    return x.f;
}

__device__ __forceinline__ ushort_t f2bf(float f) {
    union { float f; unsigned int u; } x;
    x.f = f;
    unsigned int u = x.u;
    unsigned int r = (u + 0x7FFFu + ((u >> 16) & 1u)) >> 16;  // RNE
    return (ushort_t)r;
}

__device__ __forceinline__ uint4 pack8(float4 a, float4 b) {
    uint4 u;
    u.x = (unsigned)f2bf(a.x) | ((unsigned)f2bf(a.y) << 16);
    u.y = (unsigned)f2bf(a.z) | ((unsigned)f2bf(a.w) << 16);
    u.z = (unsigned)f2bf(b.x) | ((unsigned)f2bf(b.y) << 16);
    u.w = (unsigned)f2bf(b.z) | ((unsigned)f2bf(b.w) << 16);
    return u;
}

// ---------- workspace layout (float offsets) ----------
#define F_WQ   0u          // 1638400  w       (B*L, 64)
#define F_EAQ  1638400u    // 6553600  e,a interleaved (B*L, 128, 2)
#define F_FKQ  8192000u    // 3276800  fk      (B*L, 128)
#define F_RD   11468800u   // rd as bf16 A-frag pack: 3276800 ushorts (uses half)
#define F_DIFF 14745600u   //   25600  que_diff (B*L)
#define F_PACK 14771200u   // weight bf16 pack region
#define WPACK_N 57344
#define FPACK_N 16384

// ---------- K0: pack weights into bf16 MFMA-B fragment order ----------
__global__ __launch_bounds__(256) void k_pack(
    const float* __restrict__ Mk, const float* __restrict__ eW,
    const float* __restrict__ aW, const float* __restrict__ fW,
    ushort_t* __restrict__ Wpack, ushort_t* __restrict__ Fpack)
{
    int i = blockIdx.x * 256 + threadIdx.x;
    if (i < WPACK_N) {
        int g = i >> 9, lane = (i >> 3) & 63, j = i & 7;
        int nt = g >> 2, ks = g & 3;
        int col = nt * 16 + (lane & 15);
        int d = ks * 32 + ((lane >> 4) << 3) + j;
        float v;
        if (col < 64)       v = Mk[col * 128 + d];
        else if (col < 192) v = eW[(col - 64) * 128 + d];
        else if (col < 320) v = aW[(col - 192) * 128 + d];
        else                v = fW[(col - 320) * 256 + 128 + d];  // right half: k
        Wpack[i] = f2bf(v);
    } else if (i < WPACK_N + FPACK_N) {
        int e = i - WPACK_N;
        int g = e >> 9, lane = (e >> 3) & 63, j = e & 7;
        int nt = g >> 2, ks = g & 3;
        int col = nt * 16 + (lane & 15);
        int d = ks * 32 + ((lane >> 4) << 3) + j;
        Fpack[e] = f2bf(fW[col * 256 + d]);  // left half: reads
    }
}

__device__ __forceinline__ void loadB4(const ushort_t* __restrict__ base,
                                       int nt, int lane, bf16x8* b) {
    const ushort_t* p = base + (nt * 256 + lane) * 8;
    b[0] = *(const bf16x8*)(p);
    b[1] = *(const bf16x8*)(p + 512);
    b[2] = *(const bf16x8*)(p + 1024);
    b[3] = *(const bf16x8*)(p + 1536);
}

// ---------- K1: unified MFMA gather+projections+softmax+diff ----------
__global__ __launch_bounds__(512) void k_pre_mfma(
    const int* __restrict__ q, const int* __restrict__ r,
    const float* __restrict__ k_emb, const float* __restrict__ v_emb,
    const ushort_t* __restrict__ Wpack,
    const float* __restrict__ e_b, const float* __restrict__ a_b,
    const float* __restrict__ df_W, const float* __restrict__ df_b,
    float* __restrict__ wq, float* __restrict__ eaq,
    float* __restrict__ fkq, float* __restrict__ diffq)
{
    __shared__ ushort_t skA[8192];
    __shared__ ushort_t svA[8192];
    __shared__ float slog[64 * 68];

    const int tid = threadIdx.x;
    const int pos0 = blockIdx.x * 64;
    const int wave = tid >> 6;
    const int lane = tid & 63;
    const int mt = wave & 3;
    const int nh = wave >> 2;

    // --- single gather: stage k and v A-frags (bf16) ---
    #pragma unroll
    for (int i = 0; i < 2; i++) {
        int E = tid + 512 * i;              // 1024 entries, 8 elems each
        int mtile = E >> 8, ks = (E >> 6) & 3, le = E & 63;
        int prow = pos0 + mtile * 16 + (le & 15);
        int dof = ks * 32 + ((le >> 4) << 3);
        int qv = q[prow], rv = r[prow];
        const float4* kp = (const float4*)(k_emb + qv * 128 + dof);
        float4 ka = kp[0], kb = kp[1];
        const float4* vp = (const float4*)(v_emb + rv * 128 + dof);
        float4 va = vp[0], vb = vp[1];
        *(uint4*)&skA[E * 8] = pack8(ka, kb);
        float4 s0, s1;
        s0.x = ka.x + va.x; s0.y = ka.y + va.y; s0.z = ka.z + va.z; s0.w = ka.w + va.w;
        s1.x = kb.x + vb.x; s1.y = kb.y + vb.y; s1.z = kb.z + vb.z; s1.w = kb.w + vb.w;
        *(uint4*)&svA[E * 8] = pack8(s0, s1);
    }
    __syncthreads();

    bf16x8 A[4];
    {
        const ushort_t* src = nh ? svA : skA;
        #pragma unroll
        for (int ks = 0; ks < 4; ks++)
            A[ks] = *(const bf16x8*)&src[((mt * 4 + ks) * 64 + lane) * 8];
    }

    const int col = lane & 15;
    const int quad = lane >> 4;
    const int rbase = mt * 16 + quad * 4;

    if (nh == 0) {
        bf16x8 Bb[2][4];
        loadB4(Wpack, 0, lane, Bb[0]);
        #pragma unroll
        for (int j = 0; j < 12; j++) {
            if (j < 11) {
                int jn = j + 1;
                loadB4(Wpack, (jn < 4) ? jn : jn + 16, lane, Bb[jn & 1]);
            }
            f32x4 acc = {0.f, 0.f, 0.f, 0.f};
            #pragma unroll
            for (int ks = 0; ks < 4; ks++)
                acc = __builtin_amdgcn_mfma_f32_16x16x32_bf16(A[ks], Bb[j & 1][ks], acc, 0, 0, 0);
            if (j < 4) {
                #pragma unroll
                for (int reg = 0; reg < 4; reg++)
                    slog[(rbase + reg) * 68 + j * 16 + col] = acc[reg];
            } else {
                int c = (j - 4) * 16 + col;
                #pragma unroll
                for (int reg = 0; reg < 4; reg++)
                    fkq[(pos0 + rbase + reg) * 128 + c] = acc[reg];
            }
        }
        // softmax over own wave's slog rows (wave-local)
        {
            int row = tid >> 2, ln = tid & 3;
            const float* lr = slog + row * 68 + ln * 16;
            float v[16];
            #pragma unroll
            for (int j = 0; j < 16; j++) v[j] = lr[j];
            float mx = v[0];
            #pragma unroll
            for (int j = 1; j < 16; j++) mx = fmaxf(mx, v[j]);
            mx = fmaxf(mx, __shfl_xor(mx, 1));
            mx = fmaxf(mx, __shfl_xor(mx, 2));
            float s = 0.f;
            #pragma unroll
            for (int j = 0; j < 16; j++) { v[j] = __expf(v[j] - mx); s += v[j]; }
            s += __shfl_xor(s, 1); s += __shfl_xor(s, 2);
            float inv = 1.f / s;
            float* wout = wq + (pos0 + row) * 64 + ln * 16;
            #pragma unroll
            for (int j = 0; j < 16; j++) wout[j] = v[j] * inv;
        }
    } else {
        bf16x8 Be[2][4], Ba[2][4];
        loadB4(Wpack, 4, lane, Be[0]);
        loadB4(Wpack, 12, lane, Ba[0]);
        #pragma unroll
        for (int i = 0; i < 8; i++) {
            if (i < 7) {
                loadB4(Wpack, 5 + i, lane, Be[(i + 1) & 1]);
                loadB4(Wpack, 13 + i, lane, Ba[(i + 1) & 1]);
            }
            f32x4 ae = {0.f, 0.f, 0.f, 0.f};
            f32x4 aa = {0.f, 0.f, 0.f, 0.f};
            #pragma unroll
            for (int ks = 0; ks < 4; ks++) {
                ae = __builtin_amdgcn_mfma_f32_16x16x32_bf16(A[ks], Be[i & 1][ks], ae, 0, 0, 0);
                aa = __builtin_amdgcn_mfma_f32_16x16x32_bf16(A[ks], Ba[i & 1][ks], aa, 0, 0, 0);
            }
            int c = i * 16 + col;
            float ebv = e_b[c], abv = a_b[c];
            #pragma unroll
            for (int reg = 0; reg < 4; reg++) {
                float2 o;
                o.x = fast_sigmoid(ae[reg] + ebv);
                o.y = fast_tanh(aa[reg] + abv);
                *(float2*)(eaq + ((pos0 + rbase + reg) * 128 + c) * 2) = o;
            }
        }
        // que_diff from LDS bf16 k: 4 threads/row (one per ks)
        {
            int t2 = tid - 256;
            int row = t2 >> 2, ks = t2 & 3;
            int mtile = row >> 4, rowin = row & 15;
            float s = 0.f;
            #pragma unroll
            for (int q8 = 0; q8 < 4; q8++) {
                bf16x8 kv = *(const bf16x8*)&skA[((mtile * 4 + ks) * 64 + (q8 * 16 + rowin)) * 8];
                const float* dfp = df_W + ks * 32 + q8 * 8;
                #pragma unroll
                for (int j = 0; j < 8; j++)
                    s = fmaf(bf2f((ushort_t)kv[j]), dfp[j], s);
            }
            s += __shfl_xor(s, 1); s += __shfl_xor(s, 2);
            if (ks == 0) diffq[pos0 + row] = fast_tanh(s + df_b[0]);
        }
    }
}

// ---------- K2: scan — barrier-free, intra-wave m-reduce, distance-4 reg dbuf ----------
// grid 512: b = blk>>2, dq = blk&3 (32 d). Block 256 thr = 4 waves (8 d each).
// lane = s*8+dl: s = m-octet (Mv[8]), dl = d-in-wave. Reduce = shfl_xor 8/16/32.
// s==0 lanes store reads as bf16 in MFMA A-frag order for k_final.
#define SC_PRE(wX, eX, cN)                                                 \
    _Pragma("unroll")                                                      \
    for (int tt = 0; tt < 4; tt++) {                                       \
        wX[2 * tt]     = wb4[((cN) * 4 + tt) * 16];                        \
        wX[2 * tt + 1] = wb4[((cN) * 4 + tt) * 16 + 1];                    \
        eX[tt]         = eab[((cN) * 4 + tt) * 128];                       \
    }

#define SC_CMP(wX, eX, cN)                                                 \
    _Pragma("unroll")                                                      \
    for (int tt = 0; tt < 4; tt++) {                                       \
        float4 u = wX[2 * tt], v = wX[2 * tt + 1];                         \
        float2 ea = eX[tt];                                                \
        float ev = ea.x, av = ea.y, ne = -ev;                              \
        float r0, r1;                                                      \
        r0 = u.x * Mv[0];                                                  \
        r1 = u.y * Mv[1];                                                  \
        r0 = fmaf(u.z, Mv[2], r0); r1 = fmaf(u.w, Mv[3], r1);              \
        r0 = fmaf(v.x, Mv[4], r0); r1 = fmaf(v.y, Mv[5], r1);              \
        r0 = fmaf(v.z, Mv[6], r0); r1 = fmaf(v.w, Mv[7], r1);              \
        Mv[0] = fmaf(u.x, fmaf(ne, Mv[0], av), Mv[0]);                     \
        Mv[1] = fmaf(u.y, fmaf(ne, Mv[1], av), Mv[1]);                     \
        Mv[2] = fmaf(u.z, fmaf(ne, Mv[2], av), Mv[2]);                     \
        Mv[3] = fmaf(u.w, fmaf(ne, Mv[3], av), Mv[3]);                     \
        Mv[4] = fmaf(v.x, fmaf(ne, Mv[4], av), Mv[4]);                     \
        Mv[5] = fmaf(v.y, fmaf(ne, Mv[5], av), Mv[5]);                     \
        Mv[6] = fmaf(v.z, fmaf(ne, Mv[6], av), Mv[6]);                     \
        Mv[7] = fmaf(v.w, fmaf(ne, Mv[7], av), Mv[7]);                     \
        float rd = r0 + r1;                                                \
        rd += __shfl_xor(rd, 8);                                           \
        rd += __shfl_xor(rd, 16);                                          \
        rd += __shfl_xor(rd, 32);                                          \
        if (s == 0) {                                                      \
            int pos = pos_base + (cN) * 4 + tt;                            \
            int idx = (((pos >> 4) * 4 + ksd) * 64                         \
                       + (q8d * 16 + (pos & 15))) * 8 + jd;                \
            rdpack[idx] = f2bf(rd);                                        \
        }                                                                  \
    }

__global__ __launch_bounds__(256) void k_scan(
    const float* __restrict__ wq, const float* __restrict__ eaq,
    const float* __restrict__ Mv0, ushort_t* __restrict__ rdpack)
{
    const int tid = threadIdx.x;
    const int b = blockIdx.x >> 2;
    const int dq = blockIdx.x & 3;
    const int wv = tid >> 6;      // wave -> 8-d chunk
    const int lane = tid & 63;
    const int s = lane >> 3;      // m-octet
    const int dl = lane & 7;
    const int d = dq * 32 + wv * 8 + dl;

    float Mv[8];
    #pragma unroll
    for (int j = 0; j < 8; j++) Mv[j] = Mv0[(s * 8 + j) * D_ + d];

    const float4* wb4 = (const float4*)(wq + b * (L_ * M_)) + s * 2;
    const float2* eab = (const float2*)eaq + b * (L_ * 128) + d;

    const int pos_base = b * L_;
    const int ksd = d >> 5;
    const int q8d = (d >> 3) & 3;
    const int jd = d & 7;

    float4 wA[8], wB[8];
    float2 eA[4], eB[4];

    SC_PRE(wA, eA, 0);
    for (int c = 0; c < 25; c++) {
        SC_PRE(wB, eB, 2 * c + 1);
        SC_CMP(wA, eA, 2 * c);
        if (c < 24) SC_PRE(wA, eA, 2 * c + 2);
        SC_CMP(wB, eB, 2 * c + 1);
    }
}

// ---------- K3: MFMA f-GEMM, A-frags direct from rdpack; fused ab/out ----------
__global__ __launch_bounds__(512) void k_final_mfma(
    const ushort_t* __restrict__ rdpack, const float* __restrict__ fkq,
    const float* __restrict__ diffq, const ushort_t* __restrict__ Fpack,
    const float* __restrict__ f_b, const float* __restrict__ ab_W,
    const float* __restrict__ ab_b, float* __restrict__ out)
{
    __shared__ float sab[64 * 2];

    const int tid = threadIdx.x;
    const int pos0 = blockIdx.x * 64;
    const int wave = tid >> 6;
    const int lane = tid & 63;
    const int mt = wave & 3;        // m-tile
    const int half = wave >> 2;     // nt half

    const int col = lane & 15;
    const int quad = lane >> 4;
    const int rbase = mt * 16 + quad * 4;

    bf16x8 A[4];
    {
        const ushort_t* rp = rdpack + (blockIdx.x * 4 + mt) * 2048 + lane * 8;
        #pragma unroll
        for (int ks = 0; ks < 4; ks++)
            A[ks] = *(const bf16x8*)(rp + ks * 512);
    }

    float fkv[16];
    #pragma unroll
    for (int i = 0; i < 4; i++)
        #pragma unroll
        for (int reg = 0; reg < 4; reg++)
            fkv[i * 4 + reg] = fkq[(pos0 + rbase + reg) * 128 + (half * 4 + i) * 16 + col];

    float abacc[4] = {0.f, 0.f, 0.f, 0.f};

    bf16x8 Bb[2][4];
    loadB4(Fpack, half * 4, lane, Bb[0]);
    #pragma unroll
    for (int i = 0; i < 4; i++) {
        if (i < 3) loadB4(Fpack, half * 4 + i + 1, lane, Bb[(i + 1) & 1]);
        f32x4 acc = {0.f, 0.f, 0.f, 0.f};
        #pragma unroll
        for (int ks = 0; ks < 4; ks++)
            acc = __builtin_amdgcn_mfma_f32_16x16x32_bf16(A[ks], Bb[i & 1][ks], acc, 0, 0, 0);
        int c = (half * 4 + i) * 16 + col;
        float fb = f_b[c];
        float abw = ab_W[c];
        #pragma unroll
        for (int reg = 0; reg < 4; reg++) {
            float fv = fast_tanh(acc[reg] + fkv[i * 4 + reg] + fb);
            abacc[reg] = fmaf(abw, fv, abacc[reg]);
        }
    }

    #pragma unroll
    for (int reg = 0; reg < 4; reg++) {
        float v = abacc[reg];
        v += __shfl_xor(v, 1); v += __shfl_xor(v, 2);
        v += __shfl_xor(v, 4); v += __shfl_xor(v, 8);
        abacc[reg] = v;
    }
    if (col == 0) {
        #pragma unroll
        for (int reg = 0; reg < 4; reg++)
            sab[(rbase + reg) * 2 + half] = abacc[reg];
    }
    __syncthreads();
    if (tid < 64) {
        float ab = fast_tanh(sab[tid * 2] + sab[tid * 2 + 1] + ab_b[0]);
        int pos = pos0 + tid;
        out[pos] = fast_sigmoid(3.f * ab - diffq[pos]);
    }
}

// ---------- launch ----------
extern "C" void kernel_launch(void* const* d_in, const int* in_sizes, int n_in,
                              void* d_out, int out_size, void* d_ws, size_t ws_size,
                              hipStream_t stream)
{
    const int*   q     = (const int*)d_in[0];
    const int*   r     = (const int*)d_in[1];
    const float* k_emb = (const float*)d_in[2];
    const float* v_emb = (const float*)d_in[3];
    const float* Mk    = (const float*)d_in[4];
    const float* Mv0   = (const float*)d_in[5];
    const float* f_W   = (const float*)d_in[6];
    const float* f_b   = (const float*)d_in[7];
    const float* e_W   = (const float*)d_in[8];
    const float* e_b   = (const float*)d_in[9];
    const float* a_W   = (const float*)d_in[10];
    const float* a_b   = (const float*)d_in[11];
    const float* ab_W  = (const float*)d_in[12];
    const float* ab_b  = (const float*)d_in[13];
    const float* df_W  = (const float*)d_in[14];
    const float* df_b  = (const float*)d_in[15];

    float* ws = (float*)d_ws;
    float* out = (float*)d_out;
    ushort_t* Wpack = (ushort_t*)(ws + F_PACK);
    ushort_t* Fpack = Wpack + WPACK_N;
    ushort_t* rdpack = (ushort_t*)(ws + F_RD);

    // K0: pack weights to bf16 fragment layout
    k_pack<<<288, 256, 0, stream>>>(Mk, e_W, a_W, f_W, Wpack, Fpack);

    // K1: unified MFMA projections + softmax + diff (400 blocks x 8 waves)
    k_pre_mfma<<<400, 512, 0, stream>>>(
        q, r, k_emb, v_emb, Wpack, e_b, a_b, df_W, df_b,
        ws + F_WQ, ws + F_EAQ, ws + F_FKQ, ws + F_DIFF);

    // K2: scan (128 b x 4 d-quarters, barrier-free, distance-4 dbuf)
    k_scan<<<512, 256, 0, stream>>>(
        ws + F_WQ, ws + F_EAQ, Mv0, rdpack);

    // K3: final MFMA + epilogue (400 blocks x 8 waves)
    k_final_mfma<<<400, 512, 0, stream>>>(
        rdpack, ws + F_FKQ, ws + F_DIFF, Fpack,
        f_b, ab_W, ab_b, out);
}

// Round 11
// 157.653 us; speedup vs baseline: 1.4209x; 1.0411x over previous
//
#include <hip/hip_runtime.h>

typedef unsigned short ushort_t;
typedef unsigned int uint_t;
typedef short bf16x8 __attribute__((ext_vector_type(8)));
typedef float f32x4 __attribute__((ext_vector_type(4)));

#define B_ 128
#define L_ 200
#define D_ 128
#define M_ 64

// ---------- helpers ----------
__device__ __forceinline__ float fast_sigmoid(float x) {
    return 1.f / (1.f + __expf(-x));
}

__device__ __forceinline__ float fast_tanh(float x) {
    float xc = fminf(fmaxf(x, -15.f), 15.f);
    float e = __expf(2.f * xc);
    return (e - 1.f) / (e + 1.f);
}

__device__ __forceinline__ float bf2f(ushort_t h) {
    union { unsigned int u; float f; } x;
    x.u = ((unsigned int)h) << 16;
    return x.f;
}

__device__ __forceinline__ float asf(uint_t u) {
    union { unsigned int u; float f; } x;
    x.u = u;
    return x.f;
}

__device__ __forceinline__ ushort_t f2bf(float f) {
    union { float f; unsigned int u; } x;
    x.f = f;
    unsigned int u = x.u;
    unsigned int r = (u + 0x7FFFu + ((u >> 16) & 1u)) >> 16;  // RNE
    return (ushort_t)r;
}

__device__ __forceinline__ uint4 pack8(float4 a, float4 b) {
    uint4 u;
    u.x = (unsigned)f2bf(a.x) | ((unsigned)f2bf(a.y) << 16);
    u.y = (unsigned)f2bf(a.z) | ((unsigned)f2bf(a.w) << 16);
    u.z = (unsigned)f2bf(b.x) | ((unsigned)f2bf(b.y) << 16);
    u.w = (unsigned)f2bf(b.z) | ((unsigned)f2bf(b.w) << 16);
    return u;
}

// ---------- workspace layout (float offsets) ----------
#define F_WQ   0u          // w as bf16 (B*L, 64)            : 1638400 ushorts
#define F_EAQ  1638400u    // e,a packed bf16 (B*L, 128)     : 3276800 uints
#define F_FKQ  8192000u    // fk f32 (B*L, 128)
#define F_RD   11468800u   // rd as bf16 A-frag pack
#define F_DIFF 14745600u   // que_diff f32 (B*L)
#define F_PACK 14771200u   // weight bf16 pack region
#define WPACK_N 57344
#define FPACK_N 16384

// ---------- K0: pack weights into bf16 MFMA-B fragment order ----------
__global__ __launch_bounds__(256) void k_pack(
    const float* __restrict__ Mk, const float* __restrict__ eW,
    const float* __restrict__ aW, const float* __restrict__ fW,
    ushort_t* __restrict__ Wpack, ushort_t* __restrict__ Fpack)
{
    int i = blockIdx.x * 256 + threadIdx.x;
    if (i < WPACK_N) {
        int g = i >> 9, lane = (i >> 3) & 63, j = i & 7;
        int nt = g >> 2, ks = g & 3;
        int col = nt * 16 + (lane & 15);
        int d = ks * 32 + ((lane >> 4) << 3) + j;
        float v;
        if (col < 64)       v = Mk[col * 128 + d];
        else if (col < 192) v = eW[(col - 64) * 128 + d];
        else if (col < 320) v = aW[(col - 192) * 128 + d];
        else                v = fW[(col - 320) * 256 + 128 + d];  // right half: k
        Wpack[i] = f2bf(v);
    } else if (i < WPACK_N + FPACK_N) {
        int e = i - WPACK_N;
        int g = e >> 9, lane = (e >> 3) & 63, j = e & 7;
        int nt = g >> 2, ks = g & 3;
        int col = nt * 16 + (lane & 15);
        int d = ks * 32 + ((lane >> 4) << 3) + j;
        Fpack[e] = f2bf(fW[col * 256 + d]);  // left half: reads
    }
}

__device__ __forceinline__ void loadB4(const ushort_t* __restrict__ base,
                                       int nt, int lane, bf16x8* b) {
    const ushort_t* p = base + (nt * 256 + lane) * 8;
    b[0] = *(const bf16x8*)(p);
    b[1] = *(const bf16x8*)(p + 512);
    b[2] = *(const bf16x8*)(p + 1024);
    b[3] = *(const bf16x8*)(p + 1536);
}

// ---------- K1: unified MFMA gather+projections+softmax+diff ----------
__global__ __launch_bounds__(512) void k_pre_mfma(
    const int* __restrict__ q, const int* __restrict__ r,
    const float* __restrict__ k_emb, const float* __restrict__ v_emb,
    const ushort_t* __restrict__ Wpack,
    const float* __restrict__ e_b, const float* __restrict__ a_b,
    const float* __restrict__ df_W, const float* __restrict__ df_b,
    ushort_t* __restrict__ wq, uint_t* __restrict__ eaq,
    float* __restrict__ fkq, float* __restrict__ diffq)
{
    __shared__ ushort_t skA[8192];
    __shared__ ushort_t svA[8192];
    __shared__ float slog[64 * 68];

    const int tid = threadIdx.x;
    const int pos0 = blockIdx.x * 64;
    const int wave = tid >> 6;
    const int lane = tid & 63;
    const int mt = wave & 3;
    const int nh = wave >> 2;

    // --- single gather: stage k and v A-frags (bf16) ---
    #pragma unroll
    for (int i = 0; i < 2; i++) {
        int E = tid + 512 * i;              // 1024 entries, 8 elems each
        int mtile = E >> 8, ks = (E >> 6) & 3, le = E & 63;
        int prow = pos0 + mtile * 16 + (le & 15);
        int dof = ks * 32 + ((le >> 4) << 3);
        int qv = q[prow], rv = r[prow];
        const float4* kp = (const float4*)(k_emb + qv * 128 + dof);
        float4 ka = kp[0], kb = kp[1];
        const float4* vp = (const float4*)(v_emb + rv * 128 + dof);
        float4 va = vp[0], vb = vp[1];
        *(uint4*)&skA[E * 8] = pack8(ka, kb);
        float4 s0, s1;
        s0.x = ka.x + va.x; s0.y = ka.y + va.y; s0.z = ka.z + va.z; s0.w = ka.w + va.w;
        s1.x = kb.x + vb.x; s1.y = kb.y + vb.y; s1.z = kb.z + vb.z; s1.w = kb.w + vb.w;
        *(uint4*)&svA[E * 8] = pack8(s0, s1);
    }
    __syncthreads();

    bf16x8 A[4];
    {
        const ushort_t* src = nh ? svA : skA;
        #pragma unroll
        for (int ks = 0; ks < 4; ks++)
            A[ks] = *(const bf16x8*)&src[((mt * 4 + ks) * 64 + lane) * 8];
    }

    const int col = lane & 15;
    const int quad = lane >> 4;
    const int rbase = mt * 16 + quad * 4;

    if (nh == 0) {
        bf16x8 Bb[2][4];
        loadB4(Wpack, 0, lane, Bb[0]);
        #pragma unroll
        for (int j = 0; j < 12; j++) {
            if (j < 11) {
                int jn = j + 1;
                loadB4(Wpack, (jn < 4) ? jn : jn + 16, lane, Bb[jn & 1]);
            }
            f32x4 acc = {0.f, 0.f, 0.f, 0.f};
            #pragma unroll
            for (int ks = 0; ks < 4; ks++)
                acc = __builtin_amdgcn_mfma_f32_16x16x32_bf16(A[ks], Bb[j & 1][ks], acc, 0, 0, 0);
            if (j < 4) {
                #pragma unroll
                for (int reg = 0; reg < 4; reg++)
                    slog[(rbase + reg) * 68 + j * 16 + col] = acc[reg];
            } else {
                int c = (j - 4) * 16 + col;
                #pragma unroll
                for (int reg = 0; reg < 4; reg++)
                    fkq[(pos0 + rbase + reg) * 128 + c] = acc[reg];
            }
        }
        // softmax over own wave's slog rows; store w as bf16
        {
            int row = tid >> 2, ln = tid & 3;
            const float* lr = slog + row * 68 + ln * 16;
            float v[16];
            #pragma unroll
            for (int j = 0; j < 16; j++) v[j] = lr[j];
            float mx = v[0];
            #pragma unroll
            for (int j = 1; j < 16; j++) mx = fmaxf(mx, v[j]);
            mx = fmaxf(mx, __shfl_xor(mx, 1));
            mx = fmaxf(mx, __shfl_xor(mx, 2));
            float s = 0.f;
            #pragma unroll
            for (int j = 0; j < 16; j++) { v[j] = __expf(v[j] - mx); s += v[j]; }
            s += __shfl_xor(s, 1); s += __shfl_xor(s, 2);
            float inv = 1.f / s;
            uint4 u0, u1;
            u0.x = (unsigned)f2bf(v[0] * inv)  | ((unsigned)f2bf(v[1] * inv) << 16);
            u0.y = (unsigned)f2bf(v[2] * inv)  | ((unsigned)f2bf(v[3] * inv) << 16);
            u0.z = (unsigned)f2bf(v[4] * inv)  | ((unsigned)f2bf(v[5] * inv) << 16);
            u0.w = (unsigned)f2bf(v[6] * inv)  | ((unsigned)f2bf(v[7] * inv) << 16);
            u1.x = (unsigned)f2bf(v[8] * inv)  | ((unsigned)f2bf(v[9] * inv) << 16);
            u1.y = (unsigned)f2bf(v[10] * inv) | ((unsigned)f2bf(v[11] * inv) << 16);
            u1.z = (unsigned)f2bf(v[12] * inv) | ((unsigned)f2bf(v[13] * inv) << 16);
            u1.w = (unsigned)f2bf(v[14] * inv) | ((unsigned)f2bf(v[15] * inv) << 16);
            uint4* wout = (uint4*)(wq + (pos0 + row) * 64 + ln * 16);
            wout[0] = u0;
            wout[1] = u1;
        }
    } else {
        bf16x8 Be[2][4], Ba[2][4];
        loadB4(Wpack, 4, lane, Be[0]);
        loadB4(Wpack, 12, lane, Ba[0]);
        #pragma unroll
        for (int i = 0; i < 8; i++) {
            if (i < 7) {
                loadB4(Wpack, 5 + i, lane, Be[(i + 1) & 1]);
                loadB4(Wpack, 13 + i, lane, Ba[(i + 1) & 1]);
            }
            f32x4 ae = {0.f, 0.f, 0.f, 0.f};
            f32x4 aa = {0.f, 0.f, 0.f, 0.f};
            #pragma unroll
            for (int ks = 0; ks < 4; ks++) {
                ae = __builtin_amdgcn_mfma_f32_16x16x32_bf16(A[ks], Be[i & 1][ks], ae, 0, 0, 0);
                aa = __builtin_amdgcn_mfma_f32_16x16x32_bf16(A[ks], Ba[i & 1][ks], aa, 0, 0, 0);
            }
            int c = i * 16 + col;
            float ebv = e_b[c], abv = a_b[c];
            #pragma unroll
            for (int reg = 0; reg < 4; reg++) {
                float ev = fast_sigmoid(ae[reg] + ebv);
                float av = fast_tanh(aa[reg] + abv);
                eaq[(pos0 + rbase + reg) * 128 + c] =
                    (unsigned)f2bf(ev) | ((unsigned)f2bf(av) << 16);
            }
        }
        // que_diff from LDS bf16 k: 4 threads/row (one per ks)
        {
            int t2 = tid - 256;
            int row = t2 >> 2, ks = t2 & 3;
            int mtile = row >> 4, rowin = row & 15;
            float s = 0.f;
            #pragma unroll
            for (int q8 = 0; q8 < 4; q8++) {
                bf16x8 kv = *(const bf16x8*)&skA[((mtile * 4 + ks) * 64 + (q8 * 16 + rowin)) * 8];
                const float* dfp = df_W + ks * 32 + q8 * 8;
                #pragma unroll
                for (int j = 0; j < 8; j++)
                    s = fmaf(bf2f((ushort_t)kv[j]), dfp[j], s);
            }
            s += __shfl_xor(s, 1); s += __shfl_xor(s, 2);
            if (ks == 0) diffq[pos0 + row] = fast_tanh(s + df_b[0]);
        }
    }
}

// ---------- K2: scan — barrier-free, bf16-compressed, chunk-8 reg dbuf ----------
// grid 512: b = blk>>2, dq = blk&3 (32 d). Block 256 thr = 4 waves (8 d each).
// lane = s*8+dl: s = m-octet (Mv[8]), dl = d. Reduce = shfl_xor 8/16/32.
// s==0 lanes store reads as bf16 in MFMA A-frag order for k_final.
#define SC_PRE(wX, eX, cN)                                                 \
    _Pragma("unroll")                                                      \
    for (int tt = 0; tt < 8; tt++) {                                       \
        wX[tt] = *(const uint4*)(wb + ((cN) * 8 + tt) * 64);               \
        eX[tt] = eab[((cN) * 8 + tt) * 128];                               \
    }

#define SC_CMP(wX, eX, cN)                                                 \
    _Pragma("unroll")                                                      \
    for (int tt = 0; tt < 8; tt++) {                                       \
        uint4 wu = wX[tt];                                                 \
        uint_t eu = eX[tt];                                                \
        float ev = asf(eu << 16), av = asf(eu & 0xFFFF0000u), ne = -ev;    \
        float g0 = asf(wu.x << 16), g1 = asf(wu.x & 0xFFFF0000u);          \
        float g2 = asf(wu.y << 16), g3 = asf(wu.y & 0xFFFF0000u);          \
        float g4 = asf(wu.z << 16), g5 = asf(wu.z & 0xFFFF0000u);          \
        float g6 = asf(wu.w << 16), g7 = asf(wu.w & 0xFFFF0000u);          \
        float r0, r1;                                                      \
        r0 = g0 * Mv[0];                                                   \
        r1 = g1 * Mv[1];                                                   \
        r0 = fmaf(g2, Mv[2], r0); r1 = fmaf(g3, Mv[3], r1);                \
        r0 = fmaf(g4, Mv[4], r0); r1 = fmaf(g5, Mv[5], r1);                \
        r0 = fmaf(g6, Mv[6], r0); r1 = fmaf(g7, Mv[7], r1);                \
        Mv[0] = fmaf(g0, fmaf(ne, Mv[0], av), Mv[0]);                      \
        Mv[1] = fmaf(g1, fmaf(ne, Mv[1], av), Mv[1]);                      \
        Mv[2] = fmaf(g2, fmaf(ne, Mv[2], av), Mv[2]);                      \
        Mv[3] = fmaf(g3, fmaf(ne, Mv[3], av), Mv[3]);                      \
        Mv[4] = fmaf(g4, fmaf(ne, Mv[4], av), Mv[4]);                      \
        Mv[5] = fmaf(g5, fmaf(ne, Mv[5], av), Mv[5]);                      \
        Mv[6] = fmaf(g6, fmaf(ne, Mv[6], av), Mv[6]);                      \
        Mv[7] = fmaf(g7, fmaf(ne, Mv[7], av), Mv[7]);                      \
        float rd = r0 + r1;                                                \
        rd += __shfl_xor(rd, 8);                                           \
        rd += __shfl_xor(rd, 16);                                          \
        rd += __shfl_xor(rd, 32);                                          \
        if (s == 0) {                                                      \
            int pos = pos_base + (cN) * 8 + tt;                            \
            int idx = (((pos >> 4) * 4 + ksd) * 64                         \
                       + (q8d * 16 + (pos & 15))) * 8 + jd;                \
            rdpack[idx] = f2bf(rd);                                        \
        }                                                                  \
    }

__global__ __launch_bounds__(256) void k_scan(
    const ushort_t* __restrict__ wq, const uint_t* __restrict__ eaq,
    const float* __restrict__ Mv0, ushort_t* __restrict__ rdpack)
{
    const int tid = threadIdx.x;
    const int b = blockIdx.x >> 2;
    const int dq = blockIdx.x & 3;
    const int wv = tid >> 6;      // wave -> 8-d chunk
    const int lane = tid & 63;
    const int s = lane >> 3;      // m-octet
    const int dl = lane & 7;
    const int d = dq * 32 + wv * 8 + dl;

    float Mv[8];
    #pragma unroll
    for (int j = 0; j < 8; j++) Mv[j] = Mv0[(s * 8 + j) * D_ + d];

    const ushort_t* wb = wq + b * (L_ * M_) + s * 8;
    const uint_t* eab = eaq + b * (L_ * 128) + d;

    const int pos_base = b * L_;
    const int ksd = d >> 5;
    const int q8d = (d >> 3) & 3;
    const int jd = d & 7;

    uint4 wA[8], wB[8];
    uint_t eA[8], eB[8];

    SC_PRE(wA, eA, 0);
    for (int c = 0; c < 12; c++) {
        SC_PRE(wB, eB, 2 * c + 1);
        SC_CMP(wA, eA, 2 * c);
        SC_PRE(wA, eA, 2 * c + 2);
        SC_CMP(wB, eB, 2 * c + 1);
    }
    SC_CMP(wA, eA, 24);
}

// ---------- K3: MFMA f-GEMM, A-frags direct from rdpack; fused ab/out ----------
__global__ __launch_bounds__(512) void k_final_mfma(
    const ushort_t* __restrict__ rdpack, const float* __restrict__ fkq,
    const float* __restrict__ diffq, const ushort_t* __restrict__ Fpack,
    const float* __restrict__ f_b, const float* __restrict__ ab_W,
    const float* __restrict__ ab_b, float* __restrict__ out)
{
    __shared__ float sab[64 * 2];

    const int tid = threadIdx.x;
    const int pos0 = blockIdx.x * 64;
    const int wave = tid >> 6;
    const int lane = tid & 63;
    const int mt = wave & 3;        // m-tile
    const int half = wave >> 2;     // nt half

    const int col = lane & 15;
    const int quad = lane >> 4;
    const int rbase = mt * 16 + quad * 4;

    bf16x8 A[4];
    {
        const ushort_t* rp = rdpack + (blockIdx.x * 4 + mt) * 2048 + lane * 8;
        #pragma unroll
        for (int ks = 0; ks < 4; ks++)
            A[ks] = *(const bf16x8*)(rp + ks * 512);
    }

    float fkv[16];
    #pragma unroll
    for (int i = 0; i < 4; i++)
        #pragma unroll
        for (int reg = 0; reg < 4; reg++)
            fkv[i * 4 + reg] = fkq[(pos0 + rbase + reg) * 128 + (half * 4 + i) * 16 + col];

    float abacc[4] = {0.f, 0.f, 0.f, 0.f};

    bf16x8 Bb[2][4];
    loadB4(Fpack, half * 4, lane, Bb[0]);
    #pragma unroll
    for (int i = 0; i < 4; i++) {
        if (i < 3) loadB4(Fpack, half * 4 + i + 1, lane, Bb[(i + 1) & 1]);
        f32x4 acc = {0.f, 0.f, 0.f, 0.f};
        #pragma unroll
        for (int ks = 0; ks < 4; ks++)
            acc = __builtin_amdgcn_mfma_f32_16x16x32_bf16(A[ks], Bb[i & 1][ks], acc, 0, 0, 0);
        int c = (half * 4 + i) * 16 + col;
        float fb = f_b[c];
        float abw = ab_W[c];
        #pragma unroll
        for (int reg = 0; reg < 4; reg++) {
            float fv = fast_tanh(acc[reg] + fkv[i * 4 + reg] + fb);
            abacc[reg] = fmaf(abw, fv, abacc[reg]);
        }
    }

    #pragma unroll
    for (int reg = 0; reg < 4; reg++) {
        float v = abacc[reg];
        v += __shfl_xor(v, 1); v += __shfl_xor(v, 2);
        v += __shfl_xor(v, 4); v += __shfl_xor(v, 8);
        abacc[reg] = v;
    }
    if (col == 0) {
        #pragma unroll
        for (int reg = 0; reg < 4; reg++)
            sab[(rbase + reg) * 2 + half] = abacc[reg];
    }
    __syncthreads();
    if (tid < 64) {
        float ab = fast_tanh(sab[tid * 2] + sab[tid * 2 + 1] + ab_b[0]);
        int pos = pos0 + tid;
        out[pos] = fast_sigmoid(3.f * ab - diffq[pos]);
    }
}

// ---------- launch ----------
extern "C" void kernel_launch(void* const* d_in, const int* in_sizes, int n_in,
                              void* d_out, int out_size, void* d_ws, size_t ws_size,
                              hipStream_t stream)
{
    const int*   q     = (const int*)d_in[0];
    const int*   r     = (const int*)d_in[1];
    const float* k_emb = (const float*)d_in[2];
    const float* v_emb = (const float*)d_in[3];
    const float* Mk    = (const float*)d_in[4];
    const float* Mv0   = (const float*)d_in[5];
    const float* f_W   = (const float*)d_in[6];
    const float* f_b   = (const float*)d_in[7];
    const float* e_W   = (const float*)d_in[8];
    const float* e_b   = (const float*)d_in[9];
    const float* a_W   = (const float*)d_in[10];
    const float* a_b   = (const float*)d_in[11];
    const float* ab_W  = (const float*)d_in[12];
    const float* ab_b  = (const float*)d_in[13];
    const float* df_W  = (const float*)d_in[14];
    const float* df_b  = (const float*)d_in[15];

    float* ws = (float*)d_ws;
    float* out = (float*)d_out;
    ushort_t* wq = (ushort_t*)(ws + F_WQ);
    uint_t* eaq = (uint_t*)(ws + F_EAQ);
    ushort_t* Wpack = (ushort_t*)(ws + F_PACK);
    ushort_t* Fpack = Wpack + WPACK_N;
    ushort_t* rdpack = (ushort_t*)(ws + F_RD);

    // K0: pack weights to bf16 fragment layout
    k_pack<<<288, 256, 0, stream>>>(Mk, e_W, a_W, f_W, Wpack, Fpack);

    // K1: unified MFMA projections + softmax + diff (400 blocks x 8 waves)
    k_pre_mfma<<<400, 512, 0, stream>>>(
        q, r, k_emb, v_emb, Wpack, e_b, a_b, df_W, df_b,
        wq, eaq, ws + F_FKQ, ws + F_DIFF);

    // K2: scan (128 b x 4 d-quarters, barrier-free, bf16, chunk-8 dbuf)
    k_scan<<<512, 256, 0, stream>>>(wq, eaq, Mv0, rdpack);

    // K3: final MFMA + epilogue (400 blocks x 8 waves)
    k_final_mfma<<<400, 512, 0, stream>>>(
        rdpack, ws + F_FKQ, ws + F_DIFF, Fpack,
        f_b, ab_W, ab_b, out);
}

// Round 12
// 156.950 us; speedup vs baseline: 1.4273x; 1.0045x over previous
//
#include <hip/hip_runtime.h>

typedef unsigned short ushort_t;
typedef unsigned int uint_t;
typedef short bf16x8 __attribute__((ext_vector_type(8)));
typedef float f32x4 __attribute__((ext_vector_type(4)));

#define B_ 128
#define L_ 200
#define D_ 128
#define M_ 64

// ---------- helpers ----------
__device__ __forceinline__ float fast_sigmoid(float x) {
    return 1.f / (1.f + __expf(-x));
}

__device__ __forceinline__ float fast_tanh(float x) {
    float xc = fminf(fmaxf(x, -15.f), 15.f);
    float e = __expf(2.f * xc);
    return (e - 1.f) / (e + 1.f);
}

__device__ __forceinline__ float bf2f(ushort_t h) {
    union { unsigned int u; float f; } x;
    x.u = ((unsigned int)h) << 16;
    return x.f;
}

__device__ __forceinline__ float asf(uint_t u) {
    union { unsigned int u; float f; } x;
    x.u = u;
    return x.f;
}

__device__ __forceinline__ ushort_t f2bf(float f) {
    union { float f; unsigned int u; } x;
    x.f = f;
    unsigned int u = x.u;
    unsigned int r = (u + 0x7FFFu + ((u >> 16) & 1u)) >> 16;  // RNE
    return (ushort_t)r;
}

__device__ __forceinline__ uint4 pack8(float4 a, float4 b) {
    uint4 u;
    u.x = (unsigned)f2bf(a.x) | ((unsigned)f2bf(a.y) << 16);
    u.y = (unsigned)f2bf(a.z) | ((unsigned)f2bf(a.w) << 16);
    u.z = (unsigned)f2bf(b.x) | ((unsigned)f2bf(b.y) << 16);
    u.w = (unsigned)f2bf(b.z) | ((unsigned)f2bf(b.w) << 16);
    return u;
}

// ---------- workspace layout (float offsets) ----------
#define F_WQ   0u          // w as bf16 (B*L, 64)            : 1638400 ushorts
#define F_EAQ  1638400u    // e,a packed bf16 (B*L, 128)     : 3276800 uints
#define F_FKQ  8192000u    // fk f32 (B*L, 128)
#define F_RD   11468800u   // rd as bf16 A-frag pack
#define F_DIFF 14745600u   // que_diff f32 (B*L)
#define F_PACK 14771200u   // weight bf16 pack region
#define WPACK_N 57344
#define FPACK_N 16384

// ---------- K0: pack weights into bf16 MFMA-B fragment order ----------
__global__ __launch_bounds__(256) void k_pack(
    const float* __restrict__ Mk, const float* __restrict__ eW,
    const float* __restrict__ aW, const float* __restrict__ fW,
    ushort_t* __restrict__ Wpack, ushort_t* __restrict__ Fpack)
{
    int i = blockIdx.x * 256 + threadIdx.x;
    if (i < WPACK_N) {
        int g = i >> 9, lane = (i >> 3) & 63, j = i & 7;
        int nt = g >> 2, ks = g & 3;
        int col = nt * 16 + (lane & 15);
        int d = ks * 32 + ((lane >> 4) << 3) + j;
        float v;
        if (col < 64)       v = Mk[col * 128 + d];
        else if (col < 192) v = eW[(col - 64) * 128 + d];
        else if (col < 320) v = aW[(col - 192) * 128 + d];
        else                v = fW[(col - 320) * 256 + 128 + d];  // right half: k
        Wpack[i] = f2bf(v);
    } else if (i < WPACK_N + FPACK_N) {
        int e = i - WPACK_N;
        int g = e >> 9, lane = (e >> 3) & 63, j = e & 7;
        int nt = g >> 2, ks = g & 3;
        int col = nt * 16 + (lane & 15);
        int d = ks * 32 + ((lane >> 4) << 3) + j;
        Fpack[e] = f2bf(fW[col * 256 + d]);  // left half: reads
    }
}

__device__ __forceinline__ void loadB4(const ushort_t* __restrict__ base,
                                       int nt, int lane, bf16x8* b) {
    const ushort_t* p = base + (nt * 256 + lane) * 8;
    b[0] = *(const bf16x8*)(p);
    b[1] = *(const bf16x8*)(p + 512);
    b[2] = *(const bf16x8*)(p + 1024);
    b[3] = *(const bf16x8*)(p + 1536);
}

// ---------- K1: unified MFMA gather+projections+softmax+diff ----------
__global__ __launch_bounds__(512) void k_pre_mfma(
    const int* __restrict__ q, const int* __restrict__ r,
    const float* __restrict__ k_emb, const float* __restrict__ v_emb,
    const ushort_t* __restrict__ Wpack,
    const float* __restrict__ e_b, const float* __restrict__ a_b,
    const float* __restrict__ df_W, const float* __restrict__ df_b,
    ushort_t* __restrict__ wq, uint_t* __restrict__ eaq,
    float* __restrict__ fkq, float* __restrict__ diffq)
{
    __shared__ ushort_t skA[8192];
    __shared__ ushort_t svA[8192];
    __shared__ float slog[64 * 68];

    const int tid = threadIdx.x;
    const int pos0 = blockIdx.x * 64;
    const int wave = tid >> 6;
    const int lane = tid & 63;
    const int mt = wave & 3;
    const int nh = wave >> 2;

    // --- single gather: stage k and v A-frags (bf16) ---
    #pragma unroll
    for (int i = 0; i < 2; i++) {
        int E = tid + 512 * i;              // 1024 entries, 8 elems each
        int mtile = E >> 8, ks = (E >> 6) & 3, le = E & 63;
        int prow = pos0 + mtile * 16 + (le & 15);
        int dof = ks * 32 + ((le >> 4) << 3);
        int qv = q[prow], rv = r[prow];
        const float4* kp = (const float4*)(k_emb + qv * 128 + dof);
        float4 ka = kp[0], kb = kp[1];
        const float4* vp = (const float4*)(v_emb + rv * 128 + dof);
        float4 va = vp[0], vb = vp[1];
        *(uint4*)&skA[E * 8] = pack8(ka, kb);
        float4 s0, s1;
        s0.x = ka.x + va.x; s0.y = ka.y + va.y; s0.z = ka.z + va.z; s0.w = ka.w + va.w;
        s1.x = kb.x + vb.x; s1.y = kb.y + vb.y; s1.z = kb.z + vb.z; s1.w = kb.w + vb.w;
        *(uint4*)&svA[E * 8] = pack8(s0, s1);
    }
    __syncthreads();

    bf16x8 A[4];
    {
        const ushort_t* src = nh ? svA : skA;
        #pragma unroll
        for (int ks = 0; ks < 4; ks++)
            A[ks] = *(const bf16x8*)&src[((mt * 4 + ks) * 64 + lane) * 8];
    }

    const int col = lane & 15;
    const int quad = lane >> 4;
    const int rbase = mt * 16 + quad * 4;

    if (nh == 0) {
        bf16x8 Bb[2][4];
        loadB4(Wpack, 0, lane, Bb[0]);
        #pragma unroll
        for (int j = 0; j < 12; j++) {
            if (j < 11) {
                int jn = j + 1;
                loadB4(Wpack, (jn < 4) ? jn : jn + 16, lane, Bb[jn & 1]);
            }
            f32x4 acc = {0.f, 0.f, 0.f, 0.f};
            #pragma unroll
            for (int ks = 0; ks < 4; ks++)
                acc = __builtin_amdgcn_mfma_f32_16x16x32_bf16(A[ks], Bb[j & 1][ks], acc, 0, 0, 0);
            if (j < 4) {
                #pragma unroll
                for (int reg = 0; reg < 4; reg++)
                    slog[(rbase + reg) * 68 + j * 16 + col] = acc[reg];
            } else {
                int c = (j - 4) * 16 + col;
                #pragma unroll
                for (int reg = 0; reg < 4; reg++)
                    fkq[(pos0 + rbase + reg) * 128 + c] = acc[reg];
            }
        }
        // softmax over own wave's slog rows; store w as bf16
        {
            int row = tid >> 2, ln = tid & 3;
            const float* lr = slog + row * 68 + ln * 16;
            float v[16];
            #pragma unroll
            for (int j = 0; j < 16; j++) v[j] = lr[j];
            float mx = v[0];
            #pragma unroll
            for (int j = 1; j < 16; j++) mx = fmaxf(mx, v[j]);
            mx = fmaxf(mx, __shfl_xor(mx, 1));
            mx = fmaxf(mx, __shfl_xor(mx, 2));
            float s = 0.f;
            #pragma unroll
            for (int j = 0; j < 16; j++) { v[j] = __expf(v[j] - mx); s += v[j]; }
            s += __shfl_xor(s, 1); s += __shfl_xor(s, 2);
            float inv = 1.f / s;
            uint4 u0, u1;
            u0.x = (unsigned)f2bf(v[0] * inv)  | ((unsigned)f2bf(v[1] * inv) << 16);
            u0.y = (unsigned)f2bf(v[2] * inv)  | ((unsigned)f2bf(v[3] * inv) << 16);
            u0.z = (unsigned)f2bf(v[4] * inv)  | ((unsigned)f2bf(v[5] * inv) << 16);
            u0.w = (unsigned)f2bf(v[6] * inv)  | ((unsigned)f2bf(v[7] * inv) << 16);
            u1.x = (unsigned)f2bf(v[8] * inv)  | ((unsigned)f2bf(v[9] * inv) << 16);
            u1.y = (unsigned)f2bf(v[10] * inv) | ((unsigned)f2bf(v[11] * inv) << 16);
            u1.z = (unsigned)f2bf(v[12] * inv) | ((unsigned)f2bf(v[13] * inv) << 16);
            u1.w = (unsigned)f2bf(v[14] * inv) | ((unsigned)f2bf(v[15] * inv) << 16);
            uint4* wout = (uint4*)(wq + (pos0 + row) * 64 + ln * 16);
            wout[0] = u0;
            wout[1] = u1;
        }
    } else {
        bf16x8 Be[2][4], Ba[2][4];
        loadB4(Wpack, 4, lane, Be[0]);
        loadB4(Wpack, 12, lane, Ba[0]);
        #pragma unroll
        for (int i = 0; i < 8; i++) {
            if (i < 7) {
                loadB4(Wpack, 5 + i, lane, Be[(i + 1) & 1]);
                loadB4(Wpack, 13 + i, lane, Ba[(i + 1) & 1]);
            }
            f32x4 ae = {0.f, 0.f, 0.f, 0.f};
            f32x4 aa = {0.f, 0.f, 0.f, 0.f};
            #pragma unroll
            for (int ks = 0; ks < 4; ks++) {
                ae = __builtin_amdgcn_mfma_f32_16x16x32_bf16(A[ks], Be[i & 1][ks], ae, 0, 0, 0);
                aa = __builtin_amdgcn_mfma_f32_16x16x32_bf16(A[ks], Ba[i & 1][ks], aa, 0, 0, 0);
            }
            int c = i * 16 + col;
            float ebv = e_b[c], abv = a_b[c];
            #pragma unroll
            for (int reg = 0; reg < 4; reg++) {
                float ev = fast_sigmoid(ae[reg] + ebv);
                float av = fast_tanh(aa[reg] + abv);
                eaq[(pos0 + rbase + reg) * 128 + c] =
                    (unsigned)f2bf(ev) | ((unsigned)f2bf(av) << 16);
            }
        }
        // que_diff from LDS bf16 k: 4 threads/row (one per ks)
        {
            int t2 = tid - 256;
            int row = t2 >> 2, ks = t2 & 3;
            int mtile = row >> 4, rowin = row & 15;
            float s = 0.f;
            #pragma unroll
            for (int q8 = 0; q8 < 4; q8++) {
                bf16x8 kv = *(const bf16x8*)&skA[((mtile * 4 + ks) * 64 + (q8 * 16 + rowin)) * 8];
                const float* dfp = df_W + ks * 32 + q8 * 8;
                #pragma unroll
                for (int j = 0; j < 8; j++)
                    s = fmaf(bf2f((ushort_t)kv[j]), dfp[j], s);
            }
            s += __shfl_xor(s, 1); s += __shfl_xor(s, 2);
            if (ks == 0) diffq[pos0 + row] = fast_tanh(s + df_b[0]);
        }
    }
}

// ---------- K2: scan — barrier-free, bf16, chunk-8 reg dbuf, sched-pinned ----------
// grid 512: b = blk>>2, dq = blk&3 (32 d). Block 256 thr = 4 waves (8 d each).
// lane = s*8+dl: s = m-octet (Mv[8]), dl = d. Reduce = shfl_xor 8/16/32.
// sched_barrier(0) after each prefetch group pins the loads ABOVE the compute
// of the previous chunk: no __syncthreads anywhere, so the compiler's
// fine-grained vmcnt leaves the next chunk's 16 loads in flight (never vmcnt 0).
#define SC_PRE(wX, eX, cN)                                                 \
    _Pragma("unroll")                                                      \
    for (int tt = 0; tt < 8; tt++) {                                       \
        wX[tt] = *(const uint4*)(wb + ((cN) * 8 + tt) * 64);               \
        eX[tt] = eab[((cN) * 8 + tt) * 128];                               \
    }                                                                      \
    __builtin_amdgcn_sched_barrier(0);

#define SC_CMP(wX, eX, cN)                                                 \
    _Pragma("unroll")                                                      \
    for (int tt = 0; tt < 8; tt++) {                                       \
        uint4 wu = wX[tt];                                                 \
        uint_t eu = eX[tt];                                                \
        float ev = asf(eu << 16), av = asf(eu & 0xFFFF0000u), ne = -ev;    \
        float g0 = asf(wu.x << 16), g1 = asf(wu.x & 0xFFFF0000u);          \
        float g2 = asf(wu.y << 16), g3 = asf(wu.y & 0xFFFF0000u);          \
        float g4 = asf(wu.z << 16), g5 = asf(wu.z & 0xFFFF0000u);          \
        float g6 = asf(wu.w << 16), g7 = asf(wu.w & 0xFFFF0000u);          \
        float r0, r1;                                                      \
        r0 = g0 * Mv[0];                                                   \
        r1 = g1 * Mv[1];                                                   \
        r0 = fmaf(g2, Mv[2], r0); r1 = fmaf(g3, Mv[3], r1);                \
        r0 = fmaf(g4, Mv[4], r0); r1 = fmaf(g5, Mv[5], r1);                \
        r0 = fmaf(g6, Mv[6], r0); r1 = fmaf(g7, Mv[7], r1);                \
        Mv[0] = fmaf(g0, fmaf(ne, Mv[0], av), Mv[0]);                      \
        Mv[1] = fmaf(g1, fmaf(ne, Mv[1], av), Mv[1]);                      \
        Mv[2] = fmaf(g2, fmaf(ne, Mv[2], av), Mv[2]);                      \
        Mv[3] = fmaf(g3, fmaf(ne, Mv[3], av), Mv[3]);                      \
        Mv[4] = fmaf(g4, fmaf(ne, Mv[4], av), Mv[4]);                      \
        Mv[5] = fmaf(g5, fmaf(ne, Mv[5], av), Mv[5]);                      \
        Mv[6] = fmaf(g6, fmaf(ne, Mv[6], av), Mv[6]);                      \
        Mv[7] = fmaf(g7, fmaf(ne, Mv[7], av), Mv[7]);                      \
        float rd = r0 + r1;                                                \
        rd += __shfl_xor(rd, 8);                                           \
        rd += __shfl_xor(rd, 16);                                          \
        rd += __shfl_xor(rd, 32);                                          \
        if (s == 0) {                                                      \
            int pos = pos_base + (cN) * 8 + tt;                            \
            int idx = (((pos >> 4) * 4 + ksd) * 64                         \
                       + (q8d * 16 + (pos & 15))) * 8 + jd;                \
            rdpack[idx] = f2bf(rd);                                        \
        }                                                                  \
    }

__global__ __launch_bounds__(256) void k_scan(
    const ushort_t* __restrict__ wq, const uint_t* __restrict__ eaq,
    const float* __restrict__ Mv0, ushort_t* __restrict__ rdpack)
{
    const int tid = threadIdx.x;
    const int b = blockIdx.x >> 2;
    const int dq = blockIdx.x & 3;
    const int wv = tid >> 6;      // wave -> 8-d chunk
    const int lane = tid & 63;
    const int s = lane >> 3;      // m-octet
    const int dl = lane & 7;
    const int d = dq * 32 + wv * 8 + dl;

    float Mv[8];
    #pragma unroll
    for (int j = 0; j < 8; j++) Mv[j] = Mv0[(s * 8 + j) * D_ + d];

    const ushort_t* wb = wq + b * (L_ * M_) + s * 8;
    const uint_t* eab = eaq + b * (L_ * 128) + d;

    const int pos_base = b * L_;
    const int ksd = d >> 5;
    const int q8d = (d >> 3) & 3;
    const int jd = d & 7;

    uint4 wA[8], wB[8];
    uint_t eA[8], eB[8];

    SC_PRE(wA, eA, 0);
    for (int c = 0; c < 12; c++) {
        SC_PRE(wB, eB, 2 * c + 1);
        SC_CMP(wA, eA, 2 * c);
        SC_PRE(wA, eA, 2 * c + 2);
        SC_CMP(wB, eB, 2 * c + 1);
    }
    SC_CMP(wA, eA, 24);
}

// ---------- K3: MFMA f-GEMM, A-frags direct from rdpack; fused ab/out ----------
__global__ __launch_bounds__(512) void k_final_mfma(
    const ushort_t* __restrict__ rdpack, const float* __restrict__ fkq,
    const float* __restrict__ diffq, const ushort_t* __restrict__ Fpack,
    const float* __restrict__ f_b, const float* __restrict__ ab_W,
    const float* __restrict__ ab_b, float* __restrict__ out)
{
    __shared__ float sab[64 * 2];

    const int tid = threadIdx.x;
    const int pos0 = blockIdx.x * 64;
    const int wave = tid >> 6;
    const int lane = tid & 63;
    const int mt = wave & 3;        // m-tile
    const int half = wave >> 2;     // nt half

    const int col = lane & 15;
    const int quad = lane >> 4;
    const int rbase = mt * 16 + quad * 4;

    bf16x8 A[4];
    {
        const ushort_t* rp = rdpack + (blockIdx.x * 4 + mt) * 2048 + lane * 8;
        #pragma unroll
        for (int ks = 0; ks < 4; ks++)
            A[ks] = *(const bf16x8*)(rp + ks * 512);
    }

    float fkv[16];
    #pragma unroll
    for (int i = 0; i < 4; i++)
        #pragma unroll
        for (int reg = 0; reg < 4; reg++)
            fkv[i * 4 + reg] = fkq[(pos0 + rbase + reg) * 128 + (half * 4 + i) * 16 + col];

    float abacc[4] = {0.f, 0.f, 0.f, 0.f};

    bf16x8 Bb[2][4];
    loadB4(Fpack, half * 4, lane, Bb[0]);
    #pragma unroll
    for (int i = 0; i < 4; i++) {
        if (i < 3) loadB4(Fpack, half * 4 + i + 1, lane, Bb[(i + 1) & 1]);
        f32x4 acc = {0.f, 0.f, 0.f, 0.f};
        #pragma unroll
        for (int ks = 0; ks < 4; ks++)
            acc = __builtin_amdgcn_mfma_f32_16x16x32_bf16(A[ks], Bb[i & 1][ks], acc, 0, 0, 0);
        int c = (half * 4 + i) * 16 + col;
        float fb = f_b[c];
        float abw = ab_W[c];
        #pragma unroll
        for (int reg = 0; reg < 4; reg++) {
            float fv = fast_tanh(acc[reg] + fkv[i * 4 + reg] + fb);
            abacc[reg] = fmaf(abw, fv, abacc[reg]);
        }
    }

    #pragma unroll
    for (int reg = 0; reg < 4; reg++) {
        float v = abacc[reg];
        v += __shfl_xor(v, 1); v += __shfl_xor(v, 2);
        v += __shfl_xor(v, 4); v += __shfl_xor(v, 8);
        abacc[reg] = v;
    }
    if (col == 0) {
        #pragma unroll
        for (int reg = 0; reg < 4; reg++)
            sab[(rbase + reg) * 2 + half] = abacc[reg];
    }
    __syncthreads();
    if (tid < 64) {
        float ab = fast_tanh(sab[tid * 2] + sab[tid * 2 + 1] + ab_b[0]);
        int pos = pos0 + tid;
        out[pos] = fast_sigmoid(3.f * ab - diffq[pos]);
    }
}

// ---------- launch ----------
extern "C" void kernel_launch(void* const* d_in, const int* in_sizes, int n_in,
                              void* d_out, int out_size, void* d_ws, size_t ws_size,
                              hipStream_t stream)
{
    const int*   q     = (const int*)d_in[0];
    const int*   r     = (const int*)d_in[1];
    const float* k_emb = (const float*)d_in[2];
    const float* v_emb = (const float*)d_in[3];
    const float* Mk    = (const float*)d_in[4];
    const float* Mv0   = (const float*)d_in[5];
    const float* f_W   = (const float*)d_in[6];
    const float* f_b   = (const float*)d_in[7];
    const float* e_W   = (const float*)d_in[8];
    const float* e_b   = (const float*)d_in[9];
    const float* a_W   = (const float*)d_in[10];
    const float* a_b   = (const float*)d_in[11];
    const float* ab_W  = (const float*)d_in[12];
    const float* ab_b  = (const float*)d_in[13];
    const float* df_W  = (const float*)d_in[14];
    const float* df_b  = (const float*)d_in[15];

    float* ws = (float*)d_ws;
    float* out = (float*)d_out;
    ushort_t* wq = (ushort_t*)(ws + F_WQ);
    uint_t* eaq = (uint_t*)(ws + F_EAQ);
    ushort_t* Wpack = (ushort_t*)(ws + F_PACK);
    ushort_t* Fpack = Wpack + WPACK_N;
    ushort_t* rdpack = (ushort_t*)(ws + F_RD);

    // K0: pack weights to bf16 fragment layout
    k_pack<<<288, 256, 0, stream>>>(Mk, e_W, a_W, f_W, Wpack, Fpack);

    // K1: unified MFMA projections + softmax + diff (400 blocks x 8 waves)
    k_pre_mfma<<<400, 512, 0, stream>>>(
        q, r, k_emb, v_emb, Wpack, e_b, a_b, df_W, df_b,
        wq, eaq, ws + F_FKQ, ws + F_DIFF);

    // K2: scan (128 b x 4 d-quarters, barrier-free, bf16, sched-pinned dbuf)
    k_scan<<<512, 256, 0, stream>>>(wq, eaq, Mv0, rdpack);

    // K3: final MFMA + epilogue (400 blocks x 8 waves)
    k_final_mfma<<<400, 512, 0, stream>>>(
        rdpack, ws + F_FKQ, ws + F_DIFF, Fpack,
        f_b, ab_W, ab_b, out);
}